// Round 9
// baseline (536.559 us; speedup 1.0000x reference)
//
#include <hip/hip_runtime.h>

// GraphLinear: out[b,n,o] = sum_m g[n,m] * (sum_i input[b,m,i]*W[type[m],o,i]) + bias[o]
// B=16384, N=128, DIN=DOUT=64, T=16.
// prep: bf16-convert weight/g; build groups of 16 same-type m's (NG=24, idempotent pad).
// main: 1 b-row/block, 512 threads (8 waves), 48 KiB LDS -> 3 blocks/CU.
//   Phase 0: input row staged to LDS as RAW F32 via global_load_lds DMA (no VGPR dest,
//            compiler cannot serialize it - the R4-R8 reg-staging failure mode).
//            Source address per-lane pre-swizzled (unit ^= m&15) so phase-1 reads are
//            bank-conflict-free; LDS dest linear (guide rule 21).
//   Phase 1: branch-free grouped MFMA (16 m x 1 b share one W[t]); x from LDS (cvt), W from L2.
//   Phase 2: per-wave n-tile of 16; streamed 16x16x32; contiguous dwordx4 stores.

#define NN   128
#define DI   64
#define DOUT 64
#define TT   16
#define NG   24   // compile-time padded group count (max Sum ceil(n_t/16) = 23)

typedef __attribute__((ext_vector_type(4))) float f32x4;
typedef __attribute__((ext_vector_type(8))) short bf16x8;

__device__ __forceinline__ short f2bf(float f) {
    unsigned u = __builtin_bit_cast(unsigned, f);
    u += 0x7FFFu + ((u >> 16) & 1u);   // round-to-nearest-even
    return (short)(u >> 16);
}

__device__ __forceinline__ bf16x8 cvt8(f32x4 a, f32x4 b) {
    bf16x8 r;
    r[0] = f2bf(a[0]); r[1] = f2bf(a[1]); r[2] = f2bf(a[2]); r[3] = f2bf(a[3]);
    r[4] = f2bf(b[0]); r[5] = f2bf(b[1]); r[6] = f2bf(b[2]); r[7] = f2bf(b[3]);
    return r;
}

__device__ __forceinline__ void load_lds16(const float* gp, float* lp) {
    __builtin_amdgcn_global_load_lds(
        (const __attribute__((address_space(1))) unsigned int*)gp,
        (__attribute__((address_space(3))) unsigned int*)lp, 16, 0, 0);
}

// Device-global scratch (rewritten every launch by prep_kernel; deterministic).
__device__ short d_wb[TT * DOUT * DI];   // bf16 weight [t][o][i], 128 KB (L2-hot)
__device__ short d_gb[NN * NN];          // bf16 g [n][m], 32 KB
__device__ int   d_gp[NG * 8];           // per group: m-bytes in [0..3], type in [4]

__global__ void prep_kernel(const float* __restrict__ weight,
                            const float* __restrict__ g,
                            const int*   __restrict__ ntype) {
    const int tid    = blockIdx.x * blockDim.x + threadIdx.x;
    const int stride = gridDim.x * blockDim.x;
    for (int i = tid; i < TT * DOUT * DI; i += stride) d_wb[i] = f2bf(weight[i]);
    for (int i = tid; i < NN * NN; i += stride)        d_gb[i] = f2bf(g[i]);

    if (blockIdx.x == 0) {
        __shared__ int sh_t[NN];
        const int lt = threadIdx.x;
        if (lt < NN) sh_t[lt] = ntype[lt];
        __syncthreads();
        if (lt < TT) {   // lanes 0..15 of wave 0, one type each
            int cnt = 0, m0 = 0;
            for (int m = NN - 1; m >= 0; --m)
                if (sh_t[m] == lt) { ++cnt; m0 = m; }
            const int ng = (cnt + 15) >> 4;
            int pfx = 0, total = 0;
            for (int t2 = 0; t2 < TT; ++t2) {
                const int v = __shfl(ng, t2, 64);
                if (t2 < lt) pfx += v;
                total += v;
            }
            // emit groups of 16; pad bytes pre-filled with m0 (idempotent duplicates)
            const int fill = m0 * 0x01010101;
            int Gw = pfx, cur = 0, saved = 0;
            int pk[4] = {fill, fill, fill, fill};
            int gf[4] = {fill, fill, fill, fill};
            for (int m = 0; m < NN; ++m) {
                if (sh_t[m] == lt) {
                    const int w2 = cur >> 2, s8 = (cur & 3) * 8;
                    pk[w2] = (pk[w2] & ~(0xFF << s8)) | (m << s8);
                    if (++cur == 16) {
                        for (int k2 = 0; k2 < 4; ++k2) d_gp[Gw * 8 + k2] = pk[k2];
                        d_gp[Gw * 8 + 4] = lt;
                        if (!saved) { for (int k2 = 0; k2 < 4; ++k2) gf[k2] = pk[k2]; saved = 1; }
                        ++Gw; cur = 0;
                        for (int k2 = 0; k2 < 4; ++k2) pk[k2] = fill;
                    }
                }
            }
            if (cur > 0) {
                for (int k2 = 0; k2 < 4; ++k2) d_gp[Gw * 8 + k2] = pk[k2];
                d_gp[Gw * 8 + 4] = lt;
                if (!saved) { for (int k2 = 0; k2 < 4; ++k2) gf[k2] = pk[k2]; saved = 1; }
                ++Gw;
            }
            // replicate a real group into the empty tail (idempotent padding)
            const unsigned long long msk = __ballot(ng > 0);
            if (lt == __ffsll(msk) - 1) {
                for (int gp2 = total; gp2 < NG; ++gp2) {
                    for (int k2 = 0; k2 < 4; ++k2) d_gp[gp2 * 8 + k2] = gf[k2];
                    d_gp[gp2 * 8 + 4] = lt;
                }
            }
        }
    }
}

__global__ __launch_bounds__(512, 4)
void graph_linear_main(const float* __restrict__ input,   // [B,128,64] f32
                       const float* __restrict__ bias,    // [64] f32
                       float* __restrict__ out)           // [B,128,64] f32
{
    // ibuf: one b-row, f32, [m][unit u'] where LDS unit u' holds global unit u'^(m&15)
    //       (16B units; involution applied on the GLOBAL source address, LDS linear).
    // hbuf: [o][m ^ ((o&7)<<3)] bf16.
    __shared__ float ibuf[NN * DI];      // 32 KiB
    __shared__ short hbuf[DOUT * NN];    // 16 KiB

    const int tid  = threadIdx.x;
    const int lane = tid & 63;
    const int wave = tid >> 6;        // 0..7
    const int lo   = lane & 15;
    const int hi   = lane >> 4;       // 0..3
    const size_t b = blockIdx.x;

    // ---- phase 0: DMA input row b -> ibuf (4 x 1KB chunks per wave) ----
    {
        const float* src = input + b * (NN * DI);
#pragma unroll
        for (int q = 0; q < 4; ++q) {
            const int ck = wave * 4 + q;          // 1 KiB chunk index (0..31)
            const int U  = ck * 64 + lane;        // this lane's LDS 16B-unit
            const int m  = U >> 4;
            const int up = U & 15;
            const int u  = up ^ (m & 15);         // pre-swizzled global unit
            load_lds16(src + m * 64 + u * 4, &ibuf[ck * 256]);
        }
    }
    __syncthreads();   // vmcnt(0) drain hidden by the 2 sibling blocks on this CU

    // ---- phase 1: 3 branch-free group iterations (16 same-type m's per group) ----
    const int wu = __builtin_amdgcn_readfirstlane(wave);
#pragma unroll
    for (int it = 0; it < NG / 8; ++it) {
        const int gb = (it * 8 + wu) * 8;         // wave-uniform -> s_load
        const int p0 = d_gp[gb + 0], p1 = d_gp[gb + 1];
        const int p2 = d_gp[gb + 2], p3 = d_gp[gb + 3];
        const int t  = d_gp[gb + 4];

        // A-row slot = lo -> m = byte lo of {p0..p3}
        const int ps = (lo < 8) ? ((lo < 4) ? p0 : p1) : ((lo < 12) ? p2 : p3);
        const int mA = (ps >> ((lo & 3) * 8)) & 0xFF;
        const int sA = mA & 15;
        const float* arow = &ibuf[mA * DI];
        const f32x4 r0 = *(const f32x4*)&arow[((hi * 2)     ^ sA) * 4];
        const f32x4 r1 = *(const f32x4*)&arow[((hi * 2 + 1) ^ sA) * 4];
        const f32x4 r2 = *(const f32x4*)&arow[((hi * 2 + 8) ^ sA) * 4];
        const f32x4 r3 = *(const f32x4*)&arow[((hi * 2 + 9) ^ sA) * 4];
        const bf16x8 a0 = cvt8(r0, r1);           // k = 0..31
        const bf16x8 a1 = cvt8(r2, r3);           // k = 32..63

        const short* wrow = d_wb + t * (DOUT * DI);
        f32x4 hacc[4];
#pragma unroll
        for (int ot = 0; ot < 4; ++ot) hacc[ot] = 0.0f;
#pragma unroll
        for (int ot = 0; ot < 4; ++ot) {
            const int o = ot * 16 + lo;           // B-frag col
            const bf16x8 w0 = *(const bf16x8*)(wrow + o * DI + hi * 8);
            hacc[ot] = __builtin_amdgcn_mfma_f32_16x16x32_bf16(a0, w0, hacc[ot], 0, 0, 0);
            const bf16x8 w1 = *(const bf16x8*)(wrow + o * DI + 32 + hi * 8);
            hacc[ot] = __builtin_amdgcn_mfma_f32_16x16x32_bf16(a1, w1, hacc[ot], 0, 0, 0);
        }
        // D rows r = hi*4+j -> group slot r -> m = byte j of p[hi]. Duplicates idempotent.
        const int pst = (hi < 2) ? ((hi == 0) ? p0 : p1) : ((hi == 2) ? p2 : p3);
#pragma unroll
        for (int ot = 0; ot < 4; ++ot) {
            const int o   = ot * 16 + lo;
            const int swz = (o & 7) << 3;
#pragma unroll
            for (int j = 0; j < 4; ++j) {
                const int mS = (pst >> (8 * j)) & 0xFF;
                hbuf[o * NN + (mS ^ swz)] = f2bf(hacc[ot][j]);
            }
        }
    }
    __syncthreads();

    // ---- phase 2: wave owns n-tile [wave*16, wave*16+16) ----
    const int n = wave * 16 + lo;                 // B-frag col = n
    f32x4 acc[4];
#pragma unroll
    for (int ot = 0; ot < 4; ++ot)
        acc[ot] = *(const f32x4*)(bias + ot * 16 + hi * 4);   // bias pre-added
#pragma unroll
    for (int c = 0; c < 4; ++c) {
        const bf16x8 gfr = *(const bf16x8*)(d_gb + n * NN + c * 32 + hi * 8);
#pragma unroll
        for (int ot = 0; ot < 4; ++ot) {
            const int o   = ot * 16 + lo;         // A-frag row = o
            const int pos = (c * 32 + hi * 8) ^ ((o & 7) << 3);
            const bf16x8 hfr = *(const bf16x8*)&hbuf[o * NN + pos];
            acc[ot] = __builtin_amdgcn_mfma_f32_16x16x32_bf16(hfr, gfr, acc[ot], 0, 0, 0);
        }
    }
    // D: col=lo -> n, row=hi*4+j -> o = ot*16+hi*4+j  => contiguous dwordx4
#pragma unroll
    for (int ot = 0; ot < 4; ++ot)
        *(f32x4*)&out[(b * NN + n) * DOUT + ot * 16 + hi * 4] = acc[ot];
}

extern "C" void kernel_launch(void* const* d_in, const int* in_sizes, int n_in,
                              void* d_out, int out_size, void* d_ws, size_t ws_size,
                              hipStream_t stream) {
    const float* input  = (const float*)d_in[0];
    const float* g      = (const float*)d_in[1];
    const float* weight = (const float*)d_in[2];
    const float* bias   = (const float*)d_in[3];
    const int*   ntype  = (const int*)d_in[4];
    float* out = (float*)d_out;

    const int B = in_sizes[0] / (NN * DI);   // 16384

    hipLaunchKernelGGL(prep_kernel, dim3(32), dim3(256), 0, stream, weight, g, ntype);
    hipLaunchKernelGGL(graph_linear_main, dim3(B), dim3(512), 0, stream,
                       input, bias, out);
}

// Round 10
// 387.383 us; speedup vs baseline: 1.3851x; 1.3851x over previous
//
#include <hip/hip_runtime.h>

// GraphLinear: out[b,n,o] = sum_m g[n,m] * (sum_i input[b,m,i]*W[type[m],o,i]) + bias[o]
// B=16384, N=128, DIN=DOUT=64, T=16.
// prep: bf16-convert weight/g; groups of 8 same-type m's, idempotent padding (R8's, proven).
// main: BT=4 b-rows/block, 512 threads (8 waves), 64 KiB LDS, launch_bounds(512,2):
//   256-VGPR budget so the compiler can KEEP A LOAD BURST IN FLIGHT (R4-R8: every
//   <=128-reg config sank the loads and serialized, VGPR stuck at 40-60).
//   Phase 1 (x2 half-phases): s_load 2 groups' metadata -> burst 16 independent
//     dwordx4 input loads -> cvt -> per group: 8 w-frags + 32 MFMA (8m x 4b share W[t],
//     two 16-row subsets reuse each w-frag) -> scalar b16 LDS writes (swizzled).
//   Phase 2: hoisted h-fragments (reads h ONCE: 16 ds_read_b128/wave), then 4 n-tiles
//     of g-frags + MFMA; contiguous dwordx4 stores, bias pre-added.

#define NN   128
#define DI   64
#define DOUT 64
#define BT   4
#define TT   16
#define NG   32   // padded group count (Sum ceil(n_t/8) <= 30 < 32 always)

typedef __attribute__((ext_vector_type(4))) float f32x4;
typedef __attribute__((ext_vector_type(8))) short bf16x8;

__device__ __forceinline__ short f2bf(float f) {
    unsigned u = __builtin_bit_cast(unsigned, f);
    u += 0x7FFFu + ((u >> 16) & 1u);   // round-to-nearest-even
    return (short)(u >> 16);
}

__device__ __forceinline__ bf16x8 cvt8(f32x4 a, f32x4 b) {
    bf16x8 r;
    r[0] = f2bf(a[0]); r[1] = f2bf(a[1]); r[2] = f2bf(a[2]); r[3] = f2bf(a[3]);
    r[4] = f2bf(b[0]); r[5] = f2bf(b[1]); r[6] = f2bf(b[2]); r[7] = f2bf(b[3]);
    return r;
}

// Device-global scratch (rewritten every launch by prep_kernel; deterministic).
__device__ short d_wb[TT * DOUT * DI];   // bf16 weight [t][o][i], 128 KB (L2-hot)
__device__ short d_gb[NN * NN];          // bf16 g [n][m], 32 KB
__device__ int   d_gp[NG * 4];           // {m0..3 packed, m4..7 packed, type, 0}

__global__ void prep_kernel(const float* __restrict__ weight,
                            const float* __restrict__ g,
                            const int*   __restrict__ ntype) {
    const int tid    = blockIdx.x * blockDim.x + threadIdx.x;
    const int stride = gridDim.x * blockDim.x;
    for (int i = tid; i < TT * DOUT * DI; i += stride) d_wb[i] = f2bf(weight[i]);
    for (int i = tid; i < NN * NN; i += stride)        d_gb[i] = f2bf(g[i]);

    if (blockIdx.x == 0) {
        __shared__ int sh_t[NN];
        const int lt = threadIdx.x;
        if (lt < NN) sh_t[lt] = ntype[lt];
        __syncthreads();
        if (lt < TT) {   // lanes 0..15 of wave 0, one type each
            int cnt = 0, m0 = 0;
            for (int m = NN - 1; m >= 0; --m)
                if (sh_t[m] == lt) { ++cnt; m0 = m; }
            const int ng = (cnt + 7) >> 3;
            int pfx = 0, total = 0;
            for (int t2 = 0; t2 < TT; ++t2) {
                const int v = __shfl(ng, t2, 64);
                if (t2 < lt) pfx += v;
                total += v;
            }
            // emit groups of 8; pad bytes pre-filled with m0 (idempotent duplicates)
            const int fill = m0 * 0x01010101;
            int Gw = pfx, cur = 0, p0 = fill, p1 = fill;
            int g0p0 = fill, g0p1 = fill, saved = 0;
            for (int m = 0; m < NN; ++m) {
                if (sh_t[m] == lt) {
                    if (cur < 4) p0 = (p0 & ~(0xFF << (8 * cur))) | (m << (8 * cur));
                    else         p1 = (p1 & ~(0xFF << (8 * (cur - 4)))) | (m << (8 * (cur - 4)));
                    if (++cur == 8) {
                        d_gp[Gw * 4 + 0] = p0; d_gp[Gw * 4 + 1] = p1;
                        d_gp[Gw * 4 + 2] = lt; d_gp[Gw * 4 + 3] = 0;
                        if (!saved) { g0p0 = p0; g0p1 = p1; saved = 1; }
                        ++Gw; cur = 0; p0 = fill; p1 = fill;
                    }
                }
            }
            if (cur > 0) {
                d_gp[Gw * 4 + 0] = p0; d_gp[Gw * 4 + 1] = p1;
                d_gp[Gw * 4 + 2] = lt; d_gp[Gw * 4 + 3] = 0;
                if (!saved) { g0p0 = p0; g0p1 = p1; saved = 1; }
                ++Gw;
            }
            // replicate a real group into the empty tail (idempotent padding)
            const unsigned long long msk = __ballot(ng > 0);
            if (lt == __ffsll(msk) - 1) {
                for (int gp2 = total; gp2 < NG; ++gp2) {
                    d_gp[gp2 * 4 + 0] = g0p0; d_gp[gp2 * 4 + 1] = g0p1;
                    d_gp[gp2 * 4 + 2] = lt;   d_gp[gp2 * 4 + 3] = 0;
                }
            }
        }
    }
}

__global__ __launch_bounds__(512, 2)
void graph_linear_main(const float* __restrict__ input,   // [B,128,64] f32
                       const float* __restrict__ bias,    // [64] f32
                       float* __restrict__ out)           // [B,128,64] f32
{
    // h: [b=4][o=64][m=128] bf16 = 64 KiB; m XOR-swizzled by ((o&7)<<3).
    __shared__ short hbuf[BT * DOUT * NN];

    const int tid  = threadIdx.x;
    const int lane = tid & 63;
    const int wave = tid >> 6;        // 0..7
    const int lo   = lane & 15;
    const int hi   = lane >> 4;       // 0..3
    const int b0   = blockIdx.x * BT;

    // ---------------- phase 1: grouped MFMA (8 m x 4 b per group) ----------------
    // A rows r = mi*4 + bi; subset S0 = m-slots 0..3 (p0), S1 = slots 4..7 (p1).
    const int mi_ld = lo >> 2;        // this lane's m-slot within a subset
    const int bi_ld = lo & 3;         // this lane's b
    const float* const inpb = input + (size_t)(b0 + bi_ld) * NN * DI;

#pragma unroll
    for (int u = 0; u < 2; ++u) {
        // -- wave-uniform metadata for this half-phase's 2 groups (s_load) --
        const int gA4 = __builtin_amdgcn_readfirstlane(u * 16 + wave) * 4;
        const int gB4 = __builtin_amdgcn_readfirstlane(u * 16 + 8 + wave) * 4;
        const int Ap0 = d_gp[gA4 + 0], Ap1 = d_gp[gA4 + 1], At = d_gp[gA4 + 2];
        const int Bp0 = d_gp[gB4 + 0], Bp1 = d_gp[gB4 + 1], Bt = d_gp[gB4 + 2];

        // -- 16-load burst: all independent, all issued before any consumer --
        const int mA0 = (Ap0 >> (8 * mi_ld)) & 0xFF;
        const int mA1 = (Ap1 >> (8 * mi_ld)) & 0xFF;
        const int mB0 = (Bp0 >> (8 * mi_ld)) & 0xFF;
        const int mB1 = (Bp1 >> (8 * mi_ld)) & 0xFF;
        const float* pA0 = inpb + mA0 * DI + hi * 8;
        const float* pA1 = inpb + mA1 * DI + hi * 8;
        const float* pB0 = inpb + mB0 * DI + hi * 8;
        const float* pB1 = inpb + mB1 * DI + hi * 8;
        const f32x4 xA0a = *(const f32x4*)(pA0);
        const f32x4 xA0b = *(const f32x4*)(pA0 + 4);
        const f32x4 xA0c = *(const f32x4*)(pA0 + 32);
        const f32x4 xA0d = *(const f32x4*)(pA0 + 36);
        const f32x4 xA1a = *(const f32x4*)(pA1);
        const f32x4 xA1b = *(const f32x4*)(pA1 + 4);
        const f32x4 xA1c = *(const f32x4*)(pA1 + 32);
        const f32x4 xA1d = *(const f32x4*)(pA1 + 36);
        const f32x4 xB0a = *(const f32x4*)(pB0);
        const f32x4 xB0b = *(const f32x4*)(pB0 + 4);
        const f32x4 xB0c = *(const f32x4*)(pB0 + 32);
        const f32x4 xB0d = *(const f32x4*)(pB0 + 36);
        const f32x4 xB1a = *(const f32x4*)(pB1);
        const f32x4 xB1b = *(const f32x4*)(pB1 + 4);
        const f32x4 xB1c = *(const f32x4*)(pB1 + 32);
        const f32x4 xB1d = *(const f32x4*)(pB1 + 36);

        const bf16x8 aA00 = cvt8(xA0a, xA0b), aA01 = cvt8(xA0c, xA0d);
        const bf16x8 aA10 = cvt8(xA1a, xA1b), aA11 = cvt8(xA1c, xA1d);
        const bf16x8 aB00 = cvt8(xB0a, xB0b), aB01 = cvt8(xB0c, xB0d);
        const bf16x8 aB10 = cvt8(xB1a, xB1b), aB11 = cvt8(xB1c, xB1d);

        // -- group A: 8 w-frags, 16+16 MFMA (both subsets reuse each w-frag) --
        {
            const short* wrow = d_wb + At * (DOUT * DI);
            f32x4 h0[4], h1[4];
#pragma unroll
            for (int ot = 0; ot < 4; ++ot) { h0[ot] = 0.0f; h1[ot] = 0.0f; }
#pragma unroll
            for (int ot = 0; ot < 4; ++ot) {
                const int o = ot * 16 + lo;
                const bf16x8 w0 = *(const bf16x8*)(wrow + o * DI + hi * 8);
                const bf16x8 w1 = *(const bf16x8*)(wrow + o * DI + 32 + hi * 8);
                h0[ot] = __builtin_amdgcn_mfma_f32_16x16x32_bf16(aA00, w0, h0[ot], 0, 0, 0);
                h0[ot] = __builtin_amdgcn_mfma_f32_16x16x32_bf16(aA01, w1, h0[ot], 0, 0, 0);
                h1[ot] = __builtin_amdgcn_mfma_f32_16x16x32_bf16(aA10, w0, h1[ot], 0, 0, 0);
                h1[ot] = __builtin_amdgcn_mfma_f32_16x16x32_bf16(aA11, w1, h1[ot], 0, 0, 0);
            }
            const int mS0 = (Ap0 >> (8 * hi)) & 0xFF;   // D rows r=hi*4+j -> slot hi, b=j
            const int mS1 = (Ap1 >> (8 * hi)) & 0xFF;
#pragma unroll
            for (int ot = 0; ot < 4; ++ot) {
                const int o = ot * 16 + lo;
                const int swz = (o & 7) << 3;
#pragma unroll
                for (int j = 0; j < 4; ++j) {
                    hbuf[(j * DOUT + o) * NN + (mS0 ^ swz)] = f2bf(h0[ot][j]);
                    hbuf[(j * DOUT + o) * NN + (mS1 ^ swz)] = f2bf(h1[ot][j]);
                }
            }
        }
        // -- group B --
        {
            const short* wrow = d_wb + Bt * (DOUT * DI);
            f32x4 h0[4], h1[4];
#pragma unroll
            for (int ot = 0; ot < 4; ++ot) { h0[ot] = 0.0f; h1[ot] = 0.0f; }
#pragma unroll
            for (int ot = 0; ot < 4; ++ot) {
                const int o = ot * 16 + lo;
                const bf16x8 w0 = *(const bf16x8*)(wrow + o * DI + hi * 8);
                const bf16x8 w1 = *(const bf16x8*)(wrow + o * DI + 32 + hi * 8);
                h0[ot] = __builtin_amdgcn_mfma_f32_16x16x32_bf16(aB00, w0, h0[ot], 0, 0, 0);
                h0[ot] = __builtin_amdgcn_mfma_f32_16x16x32_bf16(aB01, w1, h0[ot], 0, 0, 0);
                h1[ot] = __builtin_amdgcn_mfma_f32_16x16x32_bf16(aB10, w0, h1[ot], 0, 0, 0);
                h1[ot] = __builtin_amdgcn_mfma_f32_16x16x32_bf16(aB11, w1, h1[ot], 0, 0, 0);
            }
            const int mS0 = (Bp0 >> (8 * hi)) & 0xFF;
            const int mS1 = (Bp1 >> (8 * hi)) & 0xFF;
#pragma unroll
            for (int ot = 0; ot < 4; ++ot) {
                const int o = ot * 16 + lo;
                const int swz = (o & 7) << 3;
#pragma unroll
                for (int j = 0; j < 4; ++j) {
                    hbuf[(j * DOUT + o) * NN + (mS0 ^ swz)] = f2bf(h0[ot][j]);
                    hbuf[(j * DOUT + o) * NN + (mS1 ^ swz)] = f2bf(h1[ot][j]);
                }
            }
        }
    }
    __syncthreads();

    // ---------------- phase 2: wave -> (bi = w>>1, nh = w&1), hoisted h ----------------
    const int bi = wave >> 1;
    const int nh = wave & 1;
    const short* hrow = hbuf + bi * (DOUT * NN);

    bf16x8 hfr[4][4];   // [k-chunk][o-tile] = 64 VGPR; h read from LDS exactly once
#pragma unroll
    for (int c = 0; c < 4; ++c)
#pragma unroll
        for (int ot = 0; ot < 4; ++ot) {
            const int o   = ot * 16 + lo;
            const int pos = (c * 32 + hi * 8) ^ ((o & 7) << 3);
            hfr[c][ot] = *(const bf16x8*)&hrow[o * NN + pos];
        }

    const size_t outb = (size_t)(b0 + bi) * NN;
#pragma unroll
    for (int nt = 0; nt < 4; ++nt) {
        const int n = nh * 64 + nt * 16 + lo;              // B-frag col = n
        f32x4 acc[4];
#pragma unroll
        for (int ot = 0; ot < 4; ++ot)
            acc[ot] = *(const f32x4*)(bias + ot * 16 + hi * 4);   // bias pre-added
#pragma unroll
        for (int c = 0; c < 4; ++c) {
            const bf16x8 gfr = *(const bf16x8*)(d_gb + n * NN + c * 32 + hi * 8);
#pragma unroll
            for (int ot = 0; ot < 4; ++ot)
                acc[ot] = __builtin_amdgcn_mfma_f32_16x16x32_bf16(hfr[c][ot], gfr, acc[ot], 0, 0, 0);
        }
        // D: col=lo -> n, row=hi*4+j -> o = ot*16+hi*4+j  => contiguous dwordx4
#pragma unroll
        for (int ot = 0; ot < 4; ++ot)
            *(f32x4*)&out[(outb + n) * DOUT + ot * 16 + hi * 4] = acc[ot];
    }
}

extern "C" void kernel_launch(void* const* d_in, const int* in_sizes, int n_in,
                              void* d_out, int out_size, void* d_ws, size_t ws_size,
                              hipStream_t stream) {
    const float* input  = (const float*)d_in[0];
    const float* g      = (const float*)d_in[1];
    const float* weight = (const float*)d_in[2];
    const float* bias   = (const float*)d_in[3];
    const int*   ntype  = (const int*)d_in[4];
    float* out = (float*)d_out;

    const int B = in_sizes[0] / (NN * DI);   // 16384

    hipLaunchKernelGGL(prep_kernel, dim3(32), dim3(256), 0, stream, weight, g, ntype);
    hipLaunchKernelGGL(graph_linear_main, dim3(B / BT), dim3(512), 0, stream,
                       input, bias, out);
}